// Round 8
// baseline (6754.171 us; speedup 1.0000x reference)
//
#include <hip/hip_runtime.h>
#include <math.h>

#define TSTEPS 1024
#define HID    2048
#define IN_D   128
#define OUT_D  128
#define NWG    128
#define NTHR   512
#define NPAIRS (HID / 2)   // 1024 epoch-tagged 8B words per slot

#define LOG2PI_F 1.8378770664093453f

typedef unsigned long long u64;
typedef unsigned int       u32;

// round-to-nearest-even f32 -> bf16 (low 16 bits)
static __device__ __forceinline__ u32 bf16_rne(float f) {
    u32 u = __float_as_uint(f);
    return (u + 0x7FFFu + ((u >> 16) & 1u)) >> 16;
}
static __device__ __forceinline__ float bf16_lo(u32 payload) {
    return __uint_as_float(payload << 16);
}
static __device__ __forceinline__ float bf16_hi(u32 payload) {
    return __uint_as_float(payload & 0xFFFF0000u);
}
// fast transcendentals (v_exp_f32 + v_rcp_f32; ~1e-7 rel err, threshold 0.21)
static __device__ __forceinline__ float fast_sig(float x) {
    return __builtin_amdgcn_rcpf(1.0f + __expf(-x));
}
static __device__ __forceinline__ float fast_tanh(float x) {
    return 1.0f - 2.0f * __builtin_amdgcn_rcpf(1.0f + __expf(2.0f * x));
}

// ---------------------------------------------------------------------------
// Persistent LSTM rollout — 128 WGs x 512 threads (A/B probe: half the sync
// domains of round 6, same protocol). WG w owns cells [16w, 16w+16); wave rg
// owns cells c0=16w+2rg, c0+1 (8 gate rows); thread holds 256 f32 W_hh
// (w[4][2][32], k-slice [32*lane, 32*lane+32)).
//
// Transport (round-6 protocol, best measured): u64 pkt = 2 x bf16 h | tag32.
// Producer: threads 0..7 (one wave) publish 8 contiguous u64 = one 64B line,
// single-wave burst. Consumer: each thread polls its own 2 pkts (relaxed
// agent-scope sc1 loads; data rides with the tag), stages f32 into swizzled
// LDS, one exchange barrier, matvec, butterfly, gsum, cell update.
//
// Skew safety: every WG polls ALL 2048 cells each step (512 thr x 4 cells),
// so a producer cannot reach step t+2's publish (overwriting tag t+1) until
// every WG -- including any slow consumer -- has published t+1, which
// requires it consumed tag t. Exact-match tags therefore never deadlock.
// ---------------------------------------------------------------------------
__global__ __launch_bounds__(NTHR, 1)
void lstm_persist(const float* __restrict__ s0,
                  const float* __restrict__ Wih,
                  const float* __restrict__ Whh,
                  const float* __restrict__ bih,
                  const float* __restrict__ bhh,
                  float* __restrict__ hs_out,
                  u64* __restrict__ pairs)     // [2][NPAIRS]
{
    __shared__ __align__(16) float4 ldsH[2][HID / 4];
    __shared__ __align__(16) float  gsum[64];

    const int tid  = threadIdx.x;
    const int wg   = blockIdx.x;
    const int rg   = tid >> 6;          // wave id 0..7
    const int lane = tid & 63;
    const int c0   = wg * 16 + 2 * rg;  // wave's first cell

    // ---- weights -> registers: 4 gates x 2 cells x 32 k ----
    float w[4][2][32];
    float wihr[4][2][2];
    float breg[4][2];
#pragma unroll
    for (int m = 0; m < 4; ++m) {
#pragma unroll
        for (int b = 0; b < 2; ++b) {
            const int grow = m * HID + c0 + b;
            const float4* src = (const float4*)(Whh + (size_t)grow * HID + lane * 32);
#pragma unroll
            for (int q = 0; q < 8; ++q) {
                float4 v = src[q];
                w[m][b][4*q+0] = v.x; w[m][b][4*q+1] = v.y;
                w[m][b][4*q+2] = v.z; w[m][b][4*q+3] = v.w;
            }
            wihr[m][b][0] = Wih[(size_t)grow * IN_D + 2 * lane];
            wihr[m][b][1] = Wih[(size_t)grow * IN_D + 2 * lane + 1];
            breg[m][b]    = bih[grow] + bhh[grow];
        }
    }

    float2 c2 = make_float2(0.f, 0.f);   // threads 0..7: cells 2u, 2u+1

    for (int t = 0; t < TSTEPS; ++t) {
        // ---- W_ih @ x_t partials (no h dependency) ----
        const float2 xv = *(const float2*)(s0 + (size_t)t * IN_D + 2 * lane);
        float acc[4][2];
#pragma unroll
        for (int m = 0; m < 4; ++m)
#pragma unroll
            for (int b = 0; b < 2; ++b)
                acc[m][b] = wihr[m][b][0] * xv.x + wihr[m][b][1] * xv.y;

        // ---- poll own 2 pkts of h(t-1); data rides with the tag ----
        if (t > 0) {
            const u32 want = (u32)t;
            const u64* sp = pairs + (size_t)((t - 1) & 1) * NPAIRS + 2 * tid;
            u64 q0, q1;
            for (;;) {
                q0 = __hip_atomic_load(sp,     __ATOMIC_RELAXED, __HIP_MEMORY_SCOPE_AGENT);
                q1 = __hip_atomic_load(sp + 1, __ATOMIC_RELAXED, __HIP_MEMORY_SCOPE_AGENT);
                if ((u32)(q0 >> 32) == want && (u32)(q1 >> 32) == want) break;
                __builtin_amdgcn_s_sleep(1);
            }
            float4 hv;
            hv.x = bf16_lo((u32)q0);
            hv.y = bf16_hi((u32)q0);
            hv.z = bf16_lo((u32)q1);
            hv.w = bf16_hi((u32)q1);
            ldsH[(t - 1) & 1][tid ^ ((tid >> 3) & 7)] = hv;   // swizzled
        }
        __syncthreads();   // sync1: exchange barrier

        // ---- recurrent matvec: 8 rows x 32 k per thread ----
        if (t > 0) {
#pragma unroll
            for (int j = 0; j < 8; ++j) {
                const int p = (8 * lane + j) ^ (lane & 7);
                float4 hv = ldsH[(t - 1) & 1][p];
#pragma unroll
                for (int m = 0; m < 4; ++m)
#pragma unroll
                    for (int b = 0; b < 2; ++b) {
                        acc[m][b] += hv.x * w[m][b][4*j+0];
                        acc[m][b] += hv.y * w[m][b][4*j+1];
                        acc[m][b] += hv.z * w[m][b][4*j+2];
                        acc[m][b] += hv.w * w[m][b][4*j+3];
                    }
            }
        }

        // ---- full 64-lane butterfly on 8 accumulators ----
#pragma unroll
        for (int m = 0; m < 4; ++m)
#pragma unroll
            for (int b = 0; b < 2; ++b) {
                acc[m][b] += __shfl_xor(acc[m][b], 1);
                acc[m][b] += __shfl_xor(acc[m][b], 2);
                acc[m][b] += __shfl_xor(acc[m][b], 4);
                acc[m][b] += __shfl_xor(acc[m][b], 8);
                acc[m][b] += __shfl_xor(acc[m][b], 16);
                acc[m][b] += __shfl_xor(acc[m][b], 32);
            }
        if (lane == 0) {
            *(float4*)&gsum[rg * 8]     = make_float4(acc[0][0] + breg[0][0],
                                                      acc[1][0] + breg[1][0],
                                                      acc[2][0] + breg[2][0],
                                                      acc[3][0] + breg[3][0]);
            *(float4*)&gsum[rg * 8 + 4] = make_float4(acc[0][1] + breg[0][1],
                                                      acc[1][1] + breg[1][1],
                                                      acc[2][1] + breg[2][1],
                                                      acc[3][1] + breg[3][1]);
        }
        __syncthreads();   // sync2: gsum ready

        // ---- cell update + publish (threads 0..7, one wave, 2 cells each) ----
        if (tid < 8) {
            const float* gs = &gsum[tid * 8];
            const float i0 = fast_sig(gs[0]), f0 = fast_sig(gs[1]);
            const float g0 = fast_tanh(gs[2]), o0 = fast_sig(gs[3]);
            const float i1 = fast_sig(gs[4]), f1 = fast_sig(gs[5]);
            const float g1 = fast_tanh(gs[6]), o1 = fast_sig(gs[7]);
            c2.x = f0 * c2.x + i0 * g0;
            c2.y = f1 * c2.y + i1 * g1;
            const float h0 = o0 * fast_tanh(c2.x);
            const float h1 = o1 * fast_tanh(c2.y);
            // publish FIRST: 8 contiguous u64 from one wave = one 64B line
            const u64 pkt = (u64)(bf16_rne(h0) | (bf16_rne(h1) << 16))
                          | ((u64)(u32)(t + 1) << 32);
            __hip_atomic_store(&pairs[(size_t)(t & 1) * NPAIRS + wg * 8 + tid], pkt,
                               __ATOMIC_RELAXED, __HIP_MEMORY_SCOPE_AGENT);
            // f32 record for out_head: 8 x float2 contiguous = 64B line
            *(float2*)&hs_out[(size_t)t * HID + wg * 16 + 2 * tid] = make_float2(h0, h1);
        }
    }
}

// ---------------------------------------------------------------------------
// Output head: mu/logvar GEMV + sample + logprob. Block = 4 timesteps.
// ---------------------------------------------------------------------------
__global__ __launch_bounds__(256)
void out_head(const float* __restrict__ eps,
              const float* __restrict__ Wmu,
              const float* __restrict__ bmu,
              const float* __restrict__ Wlv,
              const float* __restrict__ blv,
              const float* __restrict__ hs,
              float* __restrict__ xs,
              float* __restrict__ lp)
{
    __shared__ __align__(16) float hlds[4][HID];
    __shared__ __align__(16) float exch[4][256];

    const int tid = threadIdx.x;
    const int t0  = blockIdx.x * 4;

    {
        const float4* src = (const float4*)(hs + (size_t)t0 * HID);
        float4* dst = (float4*)&hlds[0][0];
#pragma unroll
        for (int i = 0; i < 8; ++i)
            dst[tid + i * 256] = src[tid + i * 256];
    }
    __syncthreads();

    const int  jrow  = tid & 127;
    const bool is_lv = tid >= 128;
    const float* Wrow = (is_lv ? Wlv : Wmu) + (size_t)jrow * HID;
    const float  bias = is_lv ? blv[jrow] : bmu[jrow];

    float acc[4] = {0.f, 0.f, 0.f, 0.f};
    const float4* w4 = (const float4*)Wrow;
#pragma unroll 4
    for (int kq = 0; kq < HID / 4; ++kq) {
        float4 wv = w4[kq];
#pragma unroll
        for (int tt = 0; tt < 4; ++tt) {
            float4 hv = ((const float4*)&hlds[tt][0])[kq];
            acc[tt] += wv.x * hv.x + wv.y * hv.y + wv.z * hv.z + wv.w * hv.w;
        }
    }
#pragma unroll
    for (int tt = 0; tt < 4; ++tt) exch[tt][tid] = acc[tt] + bias;
    __syncthreads();

#pragma unroll
    for (int r = 0; r < 2; ++r) {
        const int item = tid + r * 256;
        const int tt = item >> 7;
        const int jj = item & 127;
        const int t  = t0 + tt;
        const float mu = exch[tt][jj];
        const float lv = exch[tt][128 + jj];
        const float e  = eps[(size_t)t * OUT_D + jj];
        const float sd = expf(0.5f * lv);
        const float x  = mu + sd * e;
        const float d  = (x - mu) / sd;
        const float l  = -0.5f * d * d - 0.5f * lv - 0.5f * LOG2PI_F;
        xs[(size_t)t * OUT_D + jj] = x;
        lp[(size_t)t * OUT_D + jj] = l;
    }
}

// ---------------------------------------------------------------------------
extern "C" void kernel_launch(void* const* d_in, const int* in_sizes, int n_in,
                              void* d_out, int out_size, void* d_ws, size_t ws_size,
                              hipStream_t stream)
{
    (void)in_sizes; (void)n_in; (void)out_size; (void)ws_size;

    const float* s0  = (const float*)d_in[0];
    const float* eps = (const float*)d_in[1];
    const float* Wih = (const float*)d_in[2];
    const float* Whh = (const float*)d_in[3];
    const float* bih = (const float*)d_in[4];
    const float* bhh = (const float*)d_in[5];
    const float* Wmu = (const float*)d_in[6];
    const float* bmu = (const float*)d_in[7];
    const float* Wlv = (const float*)d_in[8];
    const float* blv = (const float*)d_in[9];

    float* out = (float*)d_out;
    float* xs = out;                         // [1024][128]
    float* lp = out + TSTEPS * OUT_D;        // [1024][128]
    float* hs = out + 2 * TSTEPS * OUT_D;    // [1024][2048]

    u64* pairs = (u64*)d_ws;                 // [2][1024] x 8B = 16KB

    // zero tags each launch (tag 0 matches no wanted tag >= 1)
    (void)hipMemsetAsync(d_ws, 0, 2 * NPAIRS * sizeof(u64), stream);

    hipLaunchKernelGGL(lstm_persist, dim3(NWG), dim3(NTHR), 0, stream,
                       s0, Wih, Whh, bih, bhh, hs, pairs);

    hipLaunchKernelGGL(out_head, dim3(TSTEPS / 4), dim3(256), 0, stream,
                       eps, Wmu, bmu, Wlv, blv, hs, xs, lp);
}

// Round 9
// 4786.814 us; speedup vs baseline: 1.4110x; 1.4110x over previous
//
#include <hip/hip_runtime.h>
#include <math.h>

#define TSTEPS 1024
#define HID    2048
#define IN_D   128
#define OUT_D  128
#define NWG    256
#define NTHR   512
#define NPAIRS (HID / 2)   // 1024 epoch-tagged 8B words per slot

#define LOG2PI_F 1.8378770664093453f

typedef unsigned long long u64;
typedef unsigned int       u32;

// round-to-nearest-even f32 -> bf16 (low 16 bits)
static __device__ __forceinline__ u32 bf16_rne(float f) {
    u32 u = __float_as_uint(f);
    return (u + 0x7FFFu + ((u >> 16) & 1u)) >> 16;
}
static __device__ __forceinline__ float bf16_lo(u32 payload) {
    return __uint_as_float(payload << 16);
}
static __device__ __forceinline__ float bf16_hi(u32 payload) {
    return __uint_as_float(payload & 0xFFFF0000u);
}
// fast transcendentals (v_exp_f32 + v_rcp_f32; ~1e-7 rel err vs 0.21 threshold)
static __device__ __forceinline__ float fast_sig(float x) {
    return __builtin_amdgcn_rcpf(1.0f + __expf(-x));
}
static __device__ __forceinline__ float fast_tanh(float x) {
    return 1.0f - 2.0f * __builtin_amdgcn_rcpf(1.0f + __expf(2.0f * x));
}

// ---------------------------------------------------------------------------
// Persistent LSTM rollout — round-6 topology (best measured: 256 WGs x 512
// thr, wave rg owns cell 8w+rg, 128 f32 W_hh regs/thread, u64 packet =
// 2 x bf16 h | tag32, per-thread poll of 2 pkts) with ONE change:
// the producer tail is collapsed. No second barrier, no designated-wave
// publisher wakeup. Each wave's lane 0 updates its own cell right after its
// butterfly, deposits {f32 h, bf16 pkt} into LDS, bumps an LDS counter; the
// LAST-ARRIVING wave packs all 8 cells and issues the 4 x u64 agent-scope
// burst (32B, single lane = compact lines) + 32B f32 hs_out line.
//
// Skew safety (unchanged from r6): exact-match tags + slot parity. WG w can
// publish tag t+3 (overwriting tag t+1 in slot parity (t+1)&1) only after
// consuming tag t+2 from ALL WGs, each of which published t+2 only after all
// its threads consumed tag t+1. So no slot is overwritten before every WG
// consumed it. The LDS counter is monotonic (target 8(t+1)) -> no reset race.
// ---------------------------------------------------------------------------
__global__ __launch_bounds__(NTHR, 2)
void lstm_persist(const float* __restrict__ s0,
                  const float* __restrict__ Wih,
                  const float* __restrict__ Whh,
                  const float* __restrict__ bih,
                  const float* __restrict__ bhh,
                  float* __restrict__ hs_out,
                  u64* __restrict__ pairs)     // [2][NPAIRS]
{
    __shared__ __align__(16) float4 ldsH[2][HID / 4];
    __shared__ __align__(16) u64    cellbuf[8];   // [wave]: lo=f32 h bits, hi=pkt
    __shared__ u32 cnt;                           // monotonic arrival counter

    const int tid  = threadIdx.x;
    const int wg   = blockIdx.x;
    const int rg   = tid >> 6;     // wave id 0..7
    const int lane = tid & 63;
    const int cell = wg * 8 + rg;  // this wave's cell

    // ---- weights -> registers: 4 gate rows of `cell`, k-slice 32/lane ----
    float w[4][32];
    float wih2[4][2];
    float breg[4];
#pragma unroll
    for (int m = 0; m < 4; ++m) {
        const int grow = m * HID + cell;
        const float4* src = (const float4*)(Whh + (size_t)grow * HID + lane * 32);
#pragma unroll
        for (int q = 0; q < 8; ++q) {
            float4 v = src[q];
            w[m][4*q+0] = v.x; w[m][4*q+1] = v.y;
            w[m][4*q+2] = v.z; w[m][4*q+3] = v.w;
        }
        wih2[m][0] = Wih[(size_t)grow * IN_D + 2 * lane];
        wih2[m][1] = Wih[(size_t)grow * IN_D + 2 * lane + 1];
        breg[m]    = bih[grow] + bhh[grow];
    }

    if (tid == 0) cnt = 0;   // covered by iter-0's sync1 before first ds_add

    float c = 0.0f;          // cell state lives in lane 0 of each wave

    for (int t = 0; t < TSTEPS; ++t) {
        // ---- W_ih @ x_t partial (no h dependency) ----
        const float2 xv = *(const float2*)(s0 + (size_t)t * IN_D + 2 * lane);
        float acc[4];
#pragma unroll
        for (int m = 0; m < 4; ++m)
            acc[m] = wih2[m][0] * xv.x + wih2[m][1] * xv.y;

        // ---- poll own 2 pkts of h(t-1); data rides with the tag ----
        if (t > 0) {
            const u32 want = (u32)t;
            const u64* sp = pairs + (size_t)((t - 1) & 1) * NPAIRS + 2 * tid;
            u64 q0, q1;
            for (;;) {
                q0 = __hip_atomic_load(sp,     __ATOMIC_RELAXED, __HIP_MEMORY_SCOPE_AGENT);
                q1 = __hip_atomic_load(sp + 1, __ATOMIC_RELAXED, __HIP_MEMORY_SCOPE_AGENT);
                if ((u32)(q0 >> 32) == want && (u32)(q1 >> 32) == want) break;
                __builtin_amdgcn_s_sleep(1);
            }
            float4 hv;
            hv.x = bf16_lo((u32)q0);
            hv.y = bf16_hi((u32)q0);
            hv.z = bf16_lo((u32)q1);
            hv.w = bf16_hi((u32)q1);
            ldsH[(t - 1) & 1][tid ^ ((tid >> 3) & 7)] = hv;   // swizzled
        }
        __syncthreads();   // sync1: the ONLY barrier per step

        // ---- recurrent matvec: 4 rows x 32 k per thread ----
        if (t > 0) {
#pragma unroll
            for (int j = 0; j < 8; ++j) {
                const int p = (8 * lane + j) ^ (lane & 7);
                float4 hv = ldsH[(t - 1) & 1][p];
#pragma unroll
                for (int m = 0; m < 4; ++m) {
                    acc[m] += hv.x * w[m][4*j+0];
                    acc[m] += hv.y * w[m][4*j+1];
                    acc[m] += hv.z * w[m][4*j+2];
                    acc[m] += hv.w * w[m][4*j+3];
                }
            }
        }

        // ---- full 64-lane butterfly: complete i,f,g,o sums at lane 0 ----
#pragma unroll
        for (int m = 0; m < 4; ++m) {
            acc[m] += __shfl_xor(acc[m], 1);
            acc[m] += __shfl_xor(acc[m], 2);
            acc[m] += __shfl_xor(acc[m], 4);
            acc[m] += __shfl_xor(acc[m], 8);
            acc[m] += __shfl_xor(acc[m], 16);
            acc[m] += __shfl_xor(acc[m], 32);
        }

        // ---- in-wave cell update; last-arriving wave publishes the WG ----
        if (lane == 0) {
            const float ig = fast_sig (acc[0] + breg[0]);
            const float fg = fast_sig (acc[1] + breg[1]);
            const float gg = fast_tanh(acc[2] + breg[2]);
            const float og = fast_sig (acc[3] + breg[3]);
            c = fg * c + ig * gg;
            const float h = og * fast_tanh(c);
            const u32 pkt = (u32)(t + 1) & 0xFFFFu;   // tag low half kept in pair build
            const u32 hb  = bf16_rne(h);
            cellbuf[rg] = ((u64)((pkt << 16) | hb) << 32) | (u64)__float_as_uint(h);
            __threadfence_block();
            const u32 old = atomicAdd(&cnt, 1u);
            if (old == (u32)(8 * t + 7)) {            // I am the last wave
                __threadfence_block();
                u64 cb[8];
#pragma unroll
                for (int i = 0; i < 8; ++i) cb[i] = cellbuf[i];
                const u64 tag = ((u64)(u32)(t + 1)) << 32;
#pragma unroll
                for (int j = 0; j < 4; ++j) {
                    const u32 b0 = (u32)(cb[2*j]     >> 32) & 0xFFFFu;
                    const u32 b1 = (u32)(cb[2*j + 1] >> 32) & 0xFFFFu;
                    const u64 pair = tag | (u64)(b0 | (b1 << 16));
                    __hip_atomic_store(&pairs[(size_t)(t & 1) * NPAIRS + wg * 4 + j],
                                       pair, __ATOMIC_RELAXED, __HIP_MEMORY_SCOPE_AGENT);
                }
                // f32 record for out_head: 32B contiguous (plain cached stores,
                // flushed by kernel-end release before out_head runs)
                float* hd = hs_out + (size_t)t * HID + wg * 8;
                float4 h03, h47;
                h03.x = __uint_as_float((u32)cb[0]); h03.y = __uint_as_float((u32)cb[1]);
                h03.z = __uint_as_float((u32)cb[2]); h03.w = __uint_as_float((u32)cb[3]);
                h47.x = __uint_as_float((u32)cb[4]); h47.y = __uint_as_float((u32)cb[5]);
                h47.z = __uint_as_float((u32)cb[6]); h47.w = __uint_as_float((u32)cb[7]);
                *(float4*)(hd)     = h03;
                *(float4*)(hd + 4) = h47;
            }
        }
    }
}

// ---------------------------------------------------------------------------
// Output head: mu/logvar GEMV + sample + logprob. Block = 4 timesteps.
// ---------------------------------------------------------------------------
__global__ __launch_bounds__(256)
void out_head(const float* __restrict__ eps,
              const float* __restrict__ Wmu,
              const float* __restrict__ bmu,
              const float* __restrict__ Wlv,
              const float* __restrict__ blv,
              const float* __restrict__ hs,
              float* __restrict__ xs,
              float* __restrict__ lp)
{
    __shared__ __align__(16) float hlds[4][HID];
    __shared__ __align__(16) float exch[4][256];

    const int tid = threadIdx.x;
    const int t0  = blockIdx.x * 4;

    {
        const float4* src = (const float4*)(hs + (size_t)t0 * HID);
        float4* dst = (float4*)&hlds[0][0];
#pragma unroll
        for (int i = 0; i < 8; ++i)
            dst[tid + i * 256] = src[tid + i * 256];
    }
    __syncthreads();

    const int  jrow  = tid & 127;
    const bool is_lv = tid >= 128;
    const float* Wrow = (is_lv ? Wlv : Wmu) + (size_t)jrow * HID;
    const float  bias = is_lv ? blv[jrow] : bmu[jrow];

    float acc[4] = {0.f, 0.f, 0.f, 0.f};
    const float4* w4 = (const float4*)Wrow;
#pragma unroll 4
    for (int kq = 0; kq < HID / 4; ++kq) {
        float4 wv = w4[kq];
#pragma unroll
        for (int tt = 0; tt < 4; ++tt) {
            float4 hv = ((const float4*)&hlds[tt][0])[kq];
            acc[tt] += wv.x * hv.x + wv.y * hv.y + wv.z * hv.z + wv.w * hv.w;
        }
    }
#pragma unroll
    for (int tt = 0; tt < 4; ++tt) exch[tt][tid] = acc[tt] + bias;
    __syncthreads();

#pragma unroll
    for (int r = 0; r < 2; ++r) {
        const int item = tid + r * 256;
        const int tt = item >> 7;
        const int jj = item & 127;
        const int t  = t0 + tt;
        const float mu = exch[tt][jj];
        const float lv = exch[tt][128 + jj];
        const float e  = eps[(size_t)t * OUT_D + jj];
        const float sd = expf(0.5f * lv);
        const float x  = mu + sd * e;
        const float d  = (x - mu) / sd;
        const float l  = -0.5f * d * d - 0.5f * lv - 0.5f * LOG2PI_F;
        xs[(size_t)t * OUT_D + jj] = x;
        lp[(size_t)t * OUT_D + jj] = l;
    }
}

// ---------------------------------------------------------------------------
extern "C" void kernel_launch(void* const* d_in, const int* in_sizes, int n_in,
                              void* d_out, int out_size, void* d_ws, size_t ws_size,
                              hipStream_t stream)
{
    (void)in_sizes; (void)n_in; (void)out_size; (void)ws_size;

    const float* s0  = (const float*)d_in[0];
    const float* eps = (const float*)d_in[1];
    const float* Wih = (const float*)d_in[2];
    const float* Whh = (const float*)d_in[3];
    const float* bih = (const float*)d_in[4];
    const float* bhh = (const float*)d_in[5];
    const float* Wmu = (const float*)d_in[6];
    const float* bmu = (const float*)d_in[7];
    const float* Wlv = (const float*)d_in[8];
    const float* blv = (const float*)d_in[9];

    float* out = (float*)d_out;
    float* xs = out;                         // [1024][128]
    float* lp = out + TSTEPS * OUT_D;        // [1024][128]
    float* hs = out + 2 * TSTEPS * OUT_D;    // [1024][2048]

    u64* pairs = (u64*)d_ws;                 // [2][1024] x 8B = 16KB

    // zero tags each launch (tag 0 matches no wanted tag >= 1)
    (void)hipMemsetAsync(d_ws, 0, 2 * NPAIRS * sizeof(u64), stream);

    hipLaunchKernelGGL(lstm_persist, dim3(NWG), dim3(NTHR), 0, stream,
                       s0, Wih, Whh, bih, bhh, hs, pairs);

    hipLaunchKernelGGL(out_head, dim3(TSTEPS / 4), dim3(256), 0, stream,
                       eps, Wmu, bmu, Wlv, blv, hs, xs, lp);
}

// Round 10
// 2970.997 us; speedup vs baseline: 2.2734x; 1.6112x over previous
//
#include <hip/hip_runtime.h>
#include <math.h>

#define TSTEPS 1024
#define HID    2048
#define IN_D   128
#define OUT_D  128
#define NWG    256
#define NTHR   512
#define NPAIRS (HID / 2)   // 1024 epoch-tagged 8B words per slot

#define LOG2PI_F 1.8378770664093453f

typedef unsigned long long u64;
typedef unsigned int       u32;

// round-to-nearest-even f32 -> bf16 (low 16 bits)
static __device__ __forceinline__ u32 bf16_rne(float f) {
    u32 u = __float_as_uint(f);
    return (u + 0x7FFFu + ((u >> 16) & 1u)) >> 16;
}
static __device__ __forceinline__ float bf16_lo(u32 payload) {
    return __uint_as_float(payload << 16);
}
static __device__ __forceinline__ float bf16_hi(u32 payload) {
    return __uint_as_float(payload & 0xFFFF0000u);
}
// fast transcendentals (v_exp_f32 + v_rcp_f32; ~1e-7 rel err vs 0.21 threshold)
static __device__ __forceinline__ float fast_sig(float x) {
    return __builtin_amdgcn_rcpf(1.0f + __expf(-x));
}
static __device__ __forceinline__ float fast_tanh(float x) {
    return 1.0f - 2.0f * __builtin_amdgcn_rcpf(1.0f + __expf(2.0f * x));
}

// ---------------------------------------------------------------------------
// Persistent LSTM rollout — round-6 structure (best measured: 256 WGs x 512
// thr; wave rg computes rows li=4rg+m (gate li>>3, cell-in-WG li&7) with the
// full K=2048 via 128 f32 W_hh regs/thread; u64 packet = 2 x bf16 h | tag32;
// producer = sync2 + threads 0..3 publishing 4 contiguous u64) with ONE
// structural change:
//
//   COLLECTIVE DETECTION. Only wave 0 polls. Each of its 64 lanes loads 16
//   pairs (lane-contiguous: pairs[64j+lane], j=0..15) and the wave exits on
//   __all(16 tags == t). This kills the max-over-512-independent-pollers
//   tail (each poll iter is an L3 RTT; 512 staggered samplers add ~2-3
//   iteration periods to every step). Wave 0 then unpacks bf16->f32 and
//   stages the WHOLE ldsH itself; waves 1-7 wait at sync1. Poll traffic
//   also drops 8x (one wave per WG instead of eight).
//
// Skew safety (unchanged from r6): exact-match tags + slot parity. WG w
// publishes tag t+2 (overwriting tag t in the same parity slot) only after
// its wave 0 consumed tag t+1 from ALL WGs, which required every WG to have
// published t+1, which required every WG's wave 0 to have consumed tag t.
// So no slot is overwritten before every WG consumed it, and a consumer
// wanting tag t can never observe t+2 instead.
// ---------------------------------------------------------------------------
__global__ __launch_bounds__(NTHR)
void lstm_persist(const float* __restrict__ s0,
                  const float* __restrict__ Wih,
                  const float* __restrict__ Whh,
                  const float* __restrict__ bih,
                  const float* __restrict__ bhh,
                  float* __restrict__ hs_out,
                  u64* __restrict__ pairs)     // [2][NPAIRS]
{
    __shared__ __align__(16) float4 ldsH[2][HID / 4];
    __shared__ __align__(16) float  gsum[32];

    const int tid   = threadIdx.x;
    const int wg    = blockIdx.x;
    const int hbase = wg * 8;
    const int rg    = tid >> 6;   // wave id 0..7
    const int lane  = tid & 63;

    // ---- weights -> registers: rows li=4rg+m, k-slice [32*lane, +32) ----
    float w[4][32];
    float wih2[4][2];
    float breg[4];
#pragma unroll
    for (int m = 0; m < 4; ++m) {
        const int li = rg * 4 + m;                       // 0..31
        const int grow = (li >> 3) * HID + hbase + (li & 7);
        const float4* src = (const float4*)(Whh + (size_t)grow * HID + lane * 32);
#pragma unroll
        for (int q = 0; q < 8; ++q) {
            float4 v = src[q];
            w[m][4*q+0] = v.x; w[m][4*q+1] = v.y;
            w[m][4*q+2] = v.z; w[m][4*q+3] = v.w;
        }
        wih2[m][0] = Wih[(size_t)grow * IN_D + 2 * lane];
        wih2[m][1] = Wih[(size_t)grow * IN_D + 2 * lane + 1];
        breg[m]    = bih[grow] + bhh[grow];
    }

    float2 c2 = make_float2(0.f, 0.f);   // threads 0..3 own cells 2tid, 2tid+1

    for (int t = 0; t < TSTEPS; ++t) {
        const int slot = (t - 1) & 1;    // consumed slot (valid when t > 0)

        // ---- W_ih @ x_t partial (no h dependency) ----
        const float2 xv = *(const float2*)(s0 + (size_t)t * IN_D + 2 * lane);
        float acc[4];
#pragma unroll
        for (int m = 0; m < 4; ++m)
            acc[m] = wih2[m][0] * xv.x + wih2[m][1] * xv.y;

        // ---- collective detect + stage: wave 0 only ----
        if (t > 0 && rg == 0) {
            const u32 want = (u32)t;
            const u64* base = pairs + (size_t)slot * NPAIRS;
            u64 v[16];
            for (;;) {
                int ok = 1;
#pragma unroll
                for (int j = 0; j < 16; ++j) {
                    v[j] = __hip_atomic_load(base + 64 * j + lane,
                                             __ATOMIC_RELAXED, __HIP_MEMORY_SCOPE_AGENT);
                    ok &= ((u32)(v[j] >> 32) == want);
                }
                if (__all(ok)) break;
                __builtin_amdgcn_s_sleep(1);
            }
            // unpack 2 x bf16 per pair -> swizzled LDS (b64 writes, conflict-free)
#pragma unroll
            for (int j = 0; j < 16; ++j) {
                const int idx  = 64 * j + lane;   // pair index 0..1023
                const int cch  = idx >> 1;        // 16B chunk 0..511
                const int half = idx & 1;
                const int p    = cch ^ ((cch >> 3) & 7);
                float* dst = (float*)&ldsH[slot][p] + 2 * half;
                *(float2*)dst = make_float2(bf16_lo((u32)v[j]), bf16_hi((u32)v[j]));
            }
        }
        __syncthreads();   // sync1: ldsH staged

        // ---- recurrent matvec: 4 rows x 32 k per thread ----
        if (t > 0) {
#pragma unroll
            for (int j = 0; j < 8; ++j) {
                const int p = (8 * lane + j) ^ (lane & 7);
                float4 hv = ldsH[slot][p];
#pragma unroll
                for (int m = 0; m < 4; ++m) {
                    acc[m] += hv.x * w[m][4*j+0];
                    acc[m] += hv.y * w[m][4*j+1];
                    acc[m] += hv.z * w[m][4*j+2];
                    acc[m] += hv.w * w[m][4*j+3];
                }
            }
        }

        // ---- full 64-lane butterfly; complete row sums at lane 0 ----
#pragma unroll
        for (int m = 0; m < 4; ++m) {
            acc[m] += __shfl_xor(acc[m], 1);
            acc[m] += __shfl_xor(acc[m], 2);
            acc[m] += __shfl_xor(acc[m], 4);
            acc[m] += __shfl_xor(acc[m], 8);
            acc[m] += __shfl_xor(acc[m], 16);
            acc[m] += __shfl_xor(acc[m], 32);
        }
        if (lane == 0) {
            // gsum[li] = preact of row li (gate li>>3, cell li&7): gate-major
            *(float4*)&gsum[rg * 4] = make_float4(acc[0] + breg[0], acc[1] + breg[1],
                                                  acc[2] + breg[2], acc[3] + breg[3]);
        }
        __syncthreads();   // sync2: gsum ready

        // ---- cell update + publish (threads 0..3, one wave, 2 cells each) ----
        if (tid < 4) {
            const int j0 = 2 * tid, j1 = 2 * tid + 1;
            const float i0 = fast_sig (gsum[j0]),      i1 = fast_sig (gsum[j1]);
            const float f0 = fast_sig (gsum[8  + j0]), f1 = fast_sig (gsum[8  + j1]);
            const float g0 = fast_tanh(gsum[16 + j0]), g1 = fast_tanh(gsum[16 + j1]);
            const float o0 = fast_sig (gsum[24 + j0]), o1 = fast_sig (gsum[24 + j1]);
            c2.x = f0 * c2.x + i0 * g0;
            c2.y = f1 * c2.y + i1 * g1;
            const float h0 = o0 * fast_tanh(c2.x);
            const float h1 = o1 * fast_tanh(c2.y);
            // publish FIRST: 4 contiguous u64 from one wave = 32B burst
            const u64 pkt = (u64)(bf16_rne(h0) | (bf16_rne(h1) << 16))
                          | ((u64)(u32)(t + 1) << 32);
            __hip_atomic_store(&pairs[(size_t)(t & 1) * NPAIRS + wg * 4 + tid], pkt,
                               __ATOMIC_RELAXED, __HIP_MEMORY_SCOPE_AGENT);
            // f32 record for out_head (plain cached stores; flushed at kernel end)
            *(float2*)&hs_out[(size_t)t * HID + hbase + j0] = make_float2(h0, h1);
        }
    }
}

// ---------------------------------------------------------------------------
// Output head: mu/logvar GEMV + sample + logprob. Block = 4 timesteps.
// ---------------------------------------------------------------------------
__global__ __launch_bounds__(256)
void out_head(const float* __restrict__ eps,
              const float* __restrict__ Wmu,
              const float* __restrict__ bmu,
              const float* __restrict__ Wlv,
              const float* __restrict__ blv,
              const float* __restrict__ hs,
              float* __restrict__ xs,
              float* __restrict__ lp)
{
    __shared__ __align__(16) float hlds[4][HID];
    __shared__ __align__(16) float exch[4][256];

    const int tid = threadIdx.x;
    const int t0  = blockIdx.x * 4;

    {
        const float4* src = (const float4*)(hs + (size_t)t0 * HID);
        float4* dst = (float4*)&hlds[0][0];
#pragma unroll
        for (int i = 0; i < 8; ++i)
            dst[tid + i * 256] = src[tid + i * 256];
    }
    __syncthreads();

    const int  jrow  = tid & 127;
    const bool is_lv = tid >= 128;
    const float* Wrow = (is_lv ? Wlv : Wmu) + (size_t)jrow * HID;
    const float  bias = is_lv ? blv[jrow] : bmu[jrow];

    float acc[4] = {0.f, 0.f, 0.f, 0.f};
    const float4* w4 = (const float4*)Wrow;
#pragma unroll 4
    for (int kq = 0; kq < HID / 4; ++kq) {
        float4 wv = w4[kq];
#pragma unroll
        for (int tt = 0; tt < 4; ++tt) {
            float4 hv = ((const float4*)&hlds[tt][0])[kq];
            acc[tt] += wv.x * hv.x + wv.y * hv.y + wv.z * hv.z + wv.w * hv.w;
        }
    }
#pragma unroll
    for (int tt = 0; tt < 4; ++tt) exch[tt][tid] = acc[tt] + bias;
    __syncthreads();

#pragma unroll
    for (int r = 0; r < 2; ++r) {
        const int item = tid + r * 256;
        const int tt = item >> 7;
        const int jj = item & 127;
        const int t  = t0 + tt;
        const float mu = exch[tt][jj];
        const float lv = exch[tt][128 + jj];
        const float e  = eps[(size_t)t * OUT_D + jj];
        const float sd = expf(0.5f * lv);
        const float x  = mu + sd * e;
        const float d  = (x - mu) / sd;
        const float l  = -0.5f * d * d - 0.5f * lv - 0.5f * LOG2PI_F;
        xs[(size_t)t * OUT_D + jj] = x;
        lp[(size_t)t * OUT_D + jj] = l;
    }
}

// ---------------------------------------------------------------------------
extern "C" void kernel_launch(void* const* d_in, const int* in_sizes, int n_in,
                              void* d_out, int out_size, void* d_ws, size_t ws_size,
                              hipStream_t stream)
{
    (void)in_sizes; (void)n_in; (void)out_size; (void)ws_size;

    const float* s0  = (const float*)d_in[0];
    const float* eps = (const float*)d_in[1];
    const float* Wih = (const float*)d_in[2];
    const float* Whh = (const float*)d_in[3];
    const float* bih = (const float*)d_in[4];
    const float* bhh = (const float*)d_in[5];
    const float* Wmu = (const float*)d_in[6];
    const float* bmu = (const float*)d_in[7];
    const float* Wlv = (const float*)d_in[8];
    const float* blv = (const float*)d_in[9];

    float* out = (float*)d_out;
    float* xs = out;                         // [1024][128]
    float* lp = out + TSTEPS * OUT_D;        // [1024][128]
    float* hs = out + 2 * TSTEPS * OUT_D;    // [1024][2048]

    u64* pairs = (u64*)d_ws;                 // [2][1024] x 8B = 16KB

    // zero tags each launch (tag 0 matches no wanted tag >= 1)
    (void)hipMemsetAsync(d_ws, 0, 2 * NPAIRS * sizeof(u64), stream);

    hipLaunchKernelGGL(lstm_persist, dim3(NWG), dim3(NTHR), 0, stream,
                       s0, Wih, Whh, bih, bhh, hs, pairs);

    hipLaunchKernelGGL(out_head, dim3(TSTEPS / 4), dim3(256), 0, stream,
                       eps, Wmu, bmu, Wlv, blv, hs, xs, lp);
}